// Round 5
// baseline (393.709 us; speedup 1.0000x reference)
//
#include <hip/hip_runtime.h>
#include <hip/hip_bf16.h>

#define N_NODES 50000
#define N_EDGES 800000
#define NHEAD 4
#define DHEAD 64
#define FDIM 256   // NHEAD*DHEAD == in_feats == out_feats
#define SCANB 1024
#define NSCAN ((N_NODES + SCANB - 1) / SCANB)   // 49

typedef __attribute__((ext_vector_type(8))) short bfrag8;   // 8 bf16 (4 VGPRs)
typedef __attribute__((ext_vector_type(4))) float f32x4;    // 4 fp32 acc

// ---------------- bf16 helpers ----------------
__device__ __forceinline__ unsigned f2bf_rne(float x) {
    unsigned u = __float_as_uint(x);
    return (u + 0x7fffu + ((u >> 16) & 1u)) >> 16;
}
__device__ __forceinline__ float bf2f(unsigned u) {
    return __uint_as_float(u << 16);
}

// ---------------- CSR build ----------------
__global__ void degree_kernel(const int* __restrict__ dst, int* __restrict__ cnt, int E) {
    int e = blockIdx.x * 256 + threadIdx.x;
    if (e < E) atomicAdd(&cnt[dst[e]], 1);
}

__global__ __launch_bounds__(1024) void scan1_kernel(const int* __restrict__ cnt,
                                                     int* __restrict__ partial,
                                                     int* __restrict__ bsum, int N) {
    __shared__ int sdata[SCANB];
    int i = blockIdx.x * SCANB + (int)threadIdx.x;
    int v = (i < N) ? cnt[i] : 0;
    sdata[threadIdx.x] = v;
    __syncthreads();
    for (int off = 1; off < SCANB; off <<= 1) {
        int t = (threadIdx.x >= (unsigned)off) ? sdata[threadIdx.x - off] : 0;
        __syncthreads();
        sdata[threadIdx.x] += t;
        __syncthreads();
    }
    if (i < N) partial[i] = sdata[threadIdx.x];
    if (threadIdx.x == SCANB - 1) bsum[blockIdx.x] = sdata[SCANB - 1];
}

__global__ void scan2_kernel(const int* __restrict__ bsum, int* __restrict__ boff, int nb) {
    int lane = threadIdx.x;   // 64 threads
    int v = (lane < nb) ? bsum[lane] : 0;
#pragma unroll
    for (int off = 1; off < 64; off <<= 1) {
        int o = __shfl_up(v, off, 64);
        if (lane >= off) v += o;
    }
    int excl = __shfl_up(v, 1, 64);
    if (lane == 0) excl = 0;
    if (lane < nb) boff[lane] = excl;
}

__global__ __launch_bounds__(1024) void scan3_kernel(const int* __restrict__ partial,
                                                     const int* __restrict__ boff,
                                                     int* __restrict__ rowptr,
                                                     int* __restrict__ cursor, int N) {
    int i = blockIdx.x * SCANB + (int)threadIdx.x;
    if (i < N) {
        int inc = partial[i] + boff[blockIdx.x];
        rowptr[i + 1] = inc;
        if (i + 1 < N) cursor[i + 1] = inc;
    }
    if (i == 0) { rowptr[0] = 0; cursor[0] = 0; }
}

__global__ void scatter_kernel(const int* __restrict__ src, const int* __restrict__ dst,
                               int* __restrict__ cursor, int* __restrict__ srcs, int E) {
    int e = blockIdx.x * 256 + threadIdx.x;
    if (e < E) {
        int pos = atomicAdd(&cursor[dst[e]], 1);
        srcs[pos] = src[e];
    }
}

// ---------------- A split: fp32 -> hi/lo bf16 ----------------
__global__ void asplit_kernel(const float* __restrict__ A, ushort* __restrict__ Ah,
                              ushort* __restrict__ Al, int n4) {
    int i = blockIdx.x * 256 + threadIdx.x;
    if (i >= n4) return;
    float4 v = reinterpret_cast<const float4*>(A)[i];
    unsigned h0 = f2bf_rne(v.x), h1 = f2bf_rne(v.y), h2 = f2bf_rne(v.z), h3 = f2bf_rne(v.w);
    reinterpret_cast<ushort4*>(Ah)[i] = make_ushort4((ushort)h0, (ushort)h1, (ushort)h2, (ushort)h3);
    reinterpret_cast<ushort4*>(Al)[i] = make_ushort4(
        (ushort)(__float_as_uint(v.x - bf2f(h0)) >> 16),
        (ushort)(__float_as_uint(v.y - bf2f(h1)) >> 16),
        (ushort)(__float_as_uint(v.z - bf2f(h2)) >> 16),
        (ushort)(__float_as_uint(v.w - bf2f(h3)) >> 16));
}

// ---------------- W split+transpose: B[256][256] fp32 -> Bth/Btl[n][k] bf16 ----------------
__global__ __launch_bounds__(256) void bconv_kernel(const float* __restrict__ B,
                                                    ushort* __restrict__ Bth,
                                                    ushort* __restrict__ Btl) {
    __shared__ ushort th[16][264], tl[16][264];
    int k0 = blockIdx.x * 16;
    int n = threadIdx.x;
#pragma unroll
    for (int k = 0; k < 16; ++k) {
        float v = B[(size_t)(k0 + k) * 256 + n];
        unsigned hb = f2bf_rne(v);
        th[k][n] = (ushort)hb;
        tl[k][n] = (ushort)(__float_as_uint(v - bf2f(hb)) >> 16);
    }
    __syncthreads();
    ushort oh[16], ol[16];
#pragma unroll
    for (int k = 0; k < 16; ++k) { oh[k] = th[k][n]; ol[k] = tl[k][n]; }
#pragma unroll
    for (int q = 0; q < 4; ++q) {
        *reinterpret_cast<ushort4*>(Bth + (size_t)n * 256 + k0 + q * 4) =
            make_ushort4(oh[q*4+0], oh[q*4+1], oh[q*4+2], oh[q*4+3]);
        *reinterpret_cast<ushort4*>(Btl + (size_t)n * 256 + k0 + q * 4) =
            make_ushort4(ol[q*4+0], ol[q*4+1], ol[q*4+2], ol[q*4+3]);
    }
}

// ---------------- GEMM: Cb[M,256](bf16) = (Ah+Al) @ (Bh+Bl), split-bf16 MFMA ----------------
// Register-staged prefetch: next K-tile's global loads issue before the MFMA cluster.
__global__ __launch_bounds__(256) void gemm_mfma_kernel(const ushort* __restrict__ Ahg,
                                                        const ushort* __restrict__ Alg,
                                                        const ushort* __restrict__ Bth,
                                                        const ushort* __restrict__ Btl,
                                                        ushort* __restrict__ Cb, int M) {
    __shared__ ushort Ah[128][40], Al[128][40];   // [m][k], 80B row stride (bank-spread)
    __shared__ ushort Bh[128][40], Bl[128][40];   // [n][k]
    const int t = threadIdx.x;
    const int lane = t & 63, wave = t >> 6;
    const int wr = wave >> 1, wc = wave & 1;
    const int row0 = blockIdx.x * 128;
    const int col0 = blockIdx.y * 128;

    f32x4 acc[4][4];
#pragma unroll
    for (int i = 0; i < 4; ++i)
#pragma unroll
        for (int j = 0; j < 4; ++j) { acc[i][j].x = 0.f; acc[i][j].y = 0.f; acc[i][j].z = 0.f; acc[i][j].w = 0.f; }

    const int srow = t >> 1;            // 0..127
    const int skoff = (t & 1) * 16;     // 0 or 16
    int arow = row0 + srow; if (arow >= M) arow = M - 1;   // clamp; stores guarded
    const size_t abase = (size_t)arow * 256 + skoff;
    const size_t bbase = (size_t)(col0 + srow) * 256 + skoff;

    uint4 r0, r1, r2, r3, r4, r5, r6, r7;
#define LOADK(kk)                                                              \
    do {                                                                       \
        r0 = *reinterpret_cast<const uint4*>(Ahg + abase + (kk));              \
        r1 = *reinterpret_cast<const uint4*>(Ahg + abase + (kk) + 8);          \
        r2 = *reinterpret_cast<const uint4*>(Alg + abase + (kk));              \
        r3 = *reinterpret_cast<const uint4*>(Alg + abase + (kk) + 8);          \
        r4 = *reinterpret_cast<const uint4*>(Bth + bbase + (kk));              \
        r5 = *reinterpret_cast<const uint4*>(Bth + bbase + (kk) + 8);          \
        r6 = *reinterpret_cast<const uint4*>(Btl + bbase + (kk));              \
        r7 = *reinterpret_cast<const uint4*>(Btl + bbase + (kk) + 8);          \
    } while (0)

    LOADK(0);
#pragma unroll
    for (int kk = 0; kk < 256; kk += 32) {
        if (kk) __syncthreads();
        *reinterpret_cast<uint4*>(&Ah[srow][skoff])     = r0;
        *reinterpret_cast<uint4*>(&Ah[srow][skoff + 8]) = r1;
        *reinterpret_cast<uint4*>(&Al[srow][skoff])     = r2;
        *reinterpret_cast<uint4*>(&Al[srow][skoff + 8]) = r3;
        *reinterpret_cast<uint4*>(&Bh[srow][skoff])     = r4;
        *reinterpret_cast<uint4*>(&Bh[srow][skoff + 8]) = r5;
        *reinterpret_cast<uint4*>(&Bl[srow][skoff])     = r6;
        *reinterpret_cast<uint4*>(&Bl[srow][skoff + 8]) = r7;
        __syncthreads();
        if (kk + 32 < 256) LOADK(kk + 32);   // latency hides under MFMA below

        const int kg = (lane >> 4) * 8;
        const int rsel = lane & 15;
        bfrag8 afh[4], afl[4], bfh[4], bfl[4];
#pragma unroll
        for (int i = 0; i < 4; ++i) {
            afh[i] = *reinterpret_cast<const bfrag8*>(&Ah[wr * 64 + i * 16 + rsel][kg]);
            afl[i] = *reinterpret_cast<const bfrag8*>(&Al[wr * 64 + i * 16 + rsel][kg]);
        }
#pragma unroll
        for (int j = 0; j < 4; ++j) {
            bfh[j] = *reinterpret_cast<const bfrag8*>(&Bh[wc * 64 + j * 16 + rsel][kg]);
            bfl[j] = *reinterpret_cast<const bfrag8*>(&Bl[wc * 64 + j * 16 + rsel][kg]);
        }
#pragma unroll
        for (int i = 0; i < 4; ++i)
#pragma unroll
            for (int j = 0; j < 4; ++j) {
                acc[i][j] = __builtin_amdgcn_mfma_f32_16x16x32_bf16(afh[i], bfh[j], acc[i][j], 0, 0, 0);
                acc[i][j] = __builtin_amdgcn_mfma_f32_16x16x32_bf16(afh[i], bfl[j], acc[i][j], 0, 0, 0);
                acc[i][j] = __builtin_amdgcn_mfma_f32_16x16x32_bf16(afl[i], bfh[j], acc[i][j], 0, 0, 0);
            }
    }
#undef LOADK
    const int ccol = lane & 15;
    const int crow = (lane >> 4) * 4;
#pragma unroll
    for (int i = 0; i < 4; ++i) {
#pragma unroll
        for (int r = 0; r < 4; ++r) {
            int row = row0 + wr * 64 + i * 16 + crow + r;
            if (row >= M) continue;
#pragma unroll
            for (int j = 0; j < 4; ++j) {
                int col = col0 + wc * 64 + j * 16 + ccol;
                float val = (r == 0) ? acc[i][j].x : (r == 1) ? acc[i][j].y : (r == 2) ? acc[i][j].z : acc[i][j].w;
                Cb[(size_t)row * 256 + col] = (ushort)f2bf_rne(val);
            }
        }
    }
}

// ---------------- el/er: per-node head dots (bf16 feat) ----------------
__global__ void eler_kernel(const ushort* __restrict__ featb, const float* __restrict__ al,
                            const float* __restrict__ ar, float* __restrict__ el,
                            float* __restrict__ er, int N) {
    int node = blockIdx.x * 4 + (threadIdx.x >> 6);
    if (node >= N) return;
    int lane = threadIdx.x & 63;
    ushort4 fu = *reinterpret_cast<const ushort4*>(featb + (size_t)node * FDIM + lane * 4);
    float f0 = bf2f(fu.x), f1 = bf2f(fu.y), f2 = bf2f(fu.z), f3 = bf2f(fu.w);
    float4 a = *reinterpret_cast<const float4*>(al + lane * 4);
    float4 b = *reinterpret_cast<const float4*>(ar + lane * 4);
    float pl = f0 * a.x + f1 * a.y + f2 * a.z + f3 * a.w;
    float pr = f0 * b.x + f1 * b.y + f2 * b.z + f3 * b.w;
#pragma unroll
    for (int m = 1; m < 16; m <<= 1) {
        pl += __shfl_xor(pl, m, 64);
        pr += __shfl_xor(pr, m, 64);
    }
    if ((lane & 15) == 0) {
        int h = lane >> 4;
        el[node * NHEAD + h] = pl;
        er[node * NHEAD + h] = pr;
    }
}

// ---------------- edge weights: normalized softmax weight per (CSR pos, head) ----------------
// One wave per node; lane = 16 edges x 4 heads, each (edge,head) computed by ONE lane.
__global__ __launch_bounds__(256) void edgew_kernel(
        const float* __restrict__ el, const float* __restrict__ er,
        const int* __restrict__ rowptr, const int* __restrict__ srcs,
        float* __restrict__ w, int N) {
    int node = blockIdx.x * 4 + (threadIdx.x >> 6);
    if (node >= N) return;
    int lane = threadIdx.x & 63;
    int h = lane & 3;         // head
    int eo = lane >> 2;       // edge offset within 16-chunk
    float erh = er[(size_t)node * NHEAD + h];
    int beg = rowptr[node], end = rowptr[node + 1];

    float m = -1e30f, ls = 0.f;
    for (int base = beg; base < end; base += 16) {
        int p = base + eo;
        float x = -1e30f;
        if (p < end) {
            int s = srcs[p];
            float t = el[(size_t)s * NHEAD + h] + erh;
            x = t > 0.f ? t : 0.2f * t;
        }
        float cm = x;   // max over the 16 lanes sharing head h (lane strides 4,8,16,32)
        cm = fmaxf(cm, __shfl_xor(cm, 4, 64));
        cm = fmaxf(cm, __shfl_xor(cm, 8, 64));
        cm = fmaxf(cm, __shfl_xor(cm, 16, 64));
        cm = fmaxf(cm, __shfl_xor(cm, 32, 64));
        float mn = fmaxf(m, cm);
        ls = ls * __expf(m - mn) + ((p < end) ? __expf(x - mn) : 0.f);
        m = mn;
    }
    ls += __shfl_xor(ls, 4, 64);
    ls += __shfl_xor(ls, 8, 64);
    ls += __shfl_xor(ls, 16, 64);
    ls += __shfl_xor(ls, 32, 64);
    float dinv = ls > 0.f ? 1.0f / ls : 0.f;

    for (int base = beg; base < end; base += 16) {
        int p = base + eo;
        if (p < end) {
            int s = srcs[p];
            float t = el[(size_t)s * NHEAD + h] + erh;
            t = t > 0.f ? t : 0.2f * t;
            w[(size_t)p * NHEAD + h] = __expf(t - m) * dinv;   // 256B contiguous per chunk
        }
    }
}

// ---------------- aggregation: plain weighted gather, one wave per node ----------------
__global__ __launch_bounds__(256) void agg_kernel(
        const ushort* __restrict__ featb, const float* __restrict__ w,
        const int* __restrict__ rowptr, const int* __restrict__ srcs,
        const ushort* __restrict__ resid_h, const ushort* __restrict__ resid_l,
        float* __restrict__ outf, ushort* __restrict__ outh, ushort* __restrict__ outl,
        int N) {
    int node = blockIdx.x * 4 + (threadIdx.x >> 6);
    if (node >= N) return;
    int lane = threadIdx.x & 63;
    int head = lane >> 4;
    int beg = rowptr[node], end = rowptr[node + 1];

    float4 a0 = make_float4(0.f, 0.f, 0.f, 0.f);
    float4 a1 = make_float4(0.f, 0.f, 0.f, 0.f);
    int p = beg;
    for (; p + 1 < end; p += 2) {
        int s0 = srcs[p], s1 = srcs[p + 1];
        float w0 = w[(size_t)p * NHEAD + head];
        float w1 = w[(size_t)(p + 1) * NHEAD + head];
        ushort4 f0 = *reinterpret_cast<const ushort4*>(featb + (size_t)s0 * FDIM + lane * 4);
        ushort4 f1 = *reinterpret_cast<const ushort4*>(featb + (size_t)s1 * FDIM + lane * 4);
        a0.x = fmaf(w0, bf2f(f0.x), a0.x); a1.x = fmaf(w1, bf2f(f1.x), a1.x);
        a0.y = fmaf(w0, bf2f(f0.y), a0.y); a1.y = fmaf(w1, bf2f(f1.y), a1.y);
        a0.z = fmaf(w0, bf2f(f0.z), a0.z); a1.z = fmaf(w1, bf2f(f1.z), a1.z);
        a0.w = fmaf(w0, bf2f(f0.w), a0.w); a1.w = fmaf(w1, bf2f(f1.w), a1.w);
    }
    if (p < end) {
        int s0 = srcs[p];
        float w0 = w[(size_t)p * NHEAD + head];
        ushort4 f0 = *reinterpret_cast<const ushort4*>(featb + (size_t)s0 * FDIM + lane * 4);
        a0.x = fmaf(w0, bf2f(f0.x), a0.x);
        a0.y = fmaf(w0, bf2f(f0.y), a0.y);
        a0.z = fmaf(w0, bf2f(f0.z), a0.z);
        a0.w = fmaf(w0, bf2f(f0.w), a0.w);
    }
    float4 acc = make_float4(a0.x + a1.x, a0.y + a1.y, a0.z + a1.z, a0.w + a1.w);

    if (resid_h) {
        ushort4 rh = *reinterpret_cast<const ushort4*>(resid_h + (size_t)node * FDIM + lane * 4);
        ushort4 rl = *reinterpret_cast<const ushort4*>(resid_l + (size_t)node * FDIM + lane * 4);
        acc.x += bf2f(rh.x) + bf2f(rl.x);
        acc.y += bf2f(rh.y) + bf2f(rl.y);
        acc.z += bf2f(rh.z) + bf2f(rl.z);
        acc.w += bf2f(rh.w) + bf2f(rl.w);
    }
    acc.x = acc.x > 0.f ? acc.x : expm1f(acc.x);
    acc.y = acc.y > 0.f ? acc.y : expm1f(acc.y);
    acc.z = acc.z > 0.f ? acc.z : expm1f(acc.z);
    acc.w = acc.w > 0.f ? acc.w : expm1f(acc.w);

    if (outf) {
        *reinterpret_cast<float4*>(outf + (size_t)node * FDIM + lane * 4) = acc;
    } else {
        unsigned h0 = f2bf_rne(acc.x), h1 = f2bf_rne(acc.y), h2 = f2bf_rne(acc.z), h3 = f2bf_rne(acc.w);
        *reinterpret_cast<ushort4*>(outh + (size_t)node * FDIM + lane * 4) =
            make_ushort4((ushort)h0, (ushort)h1, (ushort)h2, (ushort)h3);
        *reinterpret_cast<ushort4*>(outl + (size_t)node * FDIM + lane * 4) = make_ushort4(
            (ushort)(__float_as_uint(acc.x - bf2f(h0)) >> 16),
            (ushort)(__float_as_uint(acc.y - bf2f(h1)) >> 16),
            (ushort)(__float_as_uint(acc.z - bf2f(h2)) >> 16),
            (ushort)(__float_as_uint(acc.w - bf2f(h3)) >> 16));
    }
}

// ---------------- launch ----------------
extern "C" void kernel_launch(void* const* d_in, const int* in_sizes, int n_in,
                              void* d_out, int out_size, void* d_ws, size_t ws_size,
                              hipStream_t stream) {
    const float* features = (const float*)d_in[0];
    const int*   src      = (const int*)d_in[1];
    const int*   dst      = (const int*)d_in[2];
    const float* W1       = (const float*)d_in[3];
    const float* al1      = (const float*)d_in[4];
    const float* ar1      = (const float*)d_in[5];
    const float* W2       = (const float*)d_in[6];
    const float* al2      = (const float*)d_in[7];
    const float* ar2      = (const float*)d_in[8];
    float* out = (float*)d_out;

    const int N = N_NODES, E = N_EDGES;

    char* ws = (char*)d_ws;
    size_t off = 0;
    auto alloc = [&](size_t bytes) -> void* {
        void* p = ws + off;
        off = (off + bytes + 255) & ~(size_t)255;
        return p;
    };
    ushort* featb  = (ushort*)alloc((size_t)N * FDIM * 2);
    ushort* Afh    = (ushort*)alloc((size_t)N * FDIM * 2);   // layer-A hi (reused: agg1 out)
    ushort* Afl    = (ushort*)alloc((size_t)N * FDIM * 2);   // layer-A lo
    float*  el     = (float*)alloc((size_t)N * NHEAD * 4);
    float*  er     = (float*)alloc((size_t)N * NHEAD * 4);
    float*  wbuf   = (float*)alloc((size_t)E * NHEAD * 4);
    int*    rowptr = (int*)alloc((size_t)(N + 1) * 4);
    int*    cnt    = (int*)alloc((size_t)N * 4);
    int*    cursor = (int*)alloc((size_t)N * 4);
    int*    partial= (int*)alloc((size_t)N * 4);
    int*    bsum   = (int*)alloc((size_t)NSCAN * 4);
    int*    boff   = (int*)alloc((size_t)NSCAN * 4);
    int*    srcs   = (int*)alloc((size_t)E * 4);
    ushort* Bth    = (ushort*)alloc((size_t)256 * 256 * 2);
    ushort* Btl    = (ushort*)alloc((size_t)256 * 256 * 2);

    const int egrid = (E + 255) / 256;
    const int ngrid4 = (N + 3) / 4;

    // ---- CSR build (by dst) ----
    hipMemsetAsync(cnt, 0, (size_t)N * 4, stream);
    degree_kernel<<<egrid, 256, 0, stream>>>(dst, cnt, E);
    scan1_kernel<<<NSCAN, SCANB, 0, stream>>>(cnt, partial, bsum, N);
    scan2_kernel<<<1, 64, 0, stream>>>(bsum, boff, NSCAN);
    scan3_kernel<<<NSCAN, SCANB, 0, stream>>>(partial, boff, rowptr, cursor, N);
    scatter_kernel<<<egrid, 256, 0, stream>>>(src, dst, cursor, srcs, E);

    // ---- input split ----
    asplit_kernel<<<(N * FDIM / 4 + 255) / 256, 256, 0, stream>>>(features, Afh, Afl, N * FDIM / 4);

    dim3 ggrid((N + 127) / 128, 2);

    // ---- layer 1 ----
    bconv_kernel<<<16, 256, 0, stream>>>(W1, Bth, Btl);
    gemm_mfma_kernel<<<ggrid, 256, 0, stream>>>(Afh, Afl, Bth, Btl, featb, N);
    eler_kernel<<<ngrid4, 256, 0, stream>>>(featb, al1, ar1, el, er, N);
    edgew_kernel<<<ngrid4, 256, 0, stream>>>(el, er, rowptr, srcs, wbuf, N);
    agg_kernel<<<ngrid4, 256, 0, stream>>>(featb, wbuf, rowptr, srcs,
                                           nullptr, nullptr, nullptr, Afh, Afl, N);

    // ---- layer 2 (residual = layer-1 output, reconstructed hi+lo) ----
    bconv_kernel<<<16, 256, 0, stream>>>(W2, Bth, Btl);
    gemm_mfma_kernel<<<ggrid, 256, 0, stream>>>(Afh, Afl, Bth, Btl, featb, N);
    eler_kernel<<<ngrid4, 256, 0, stream>>>(featb, al2, ar2, el, er, N);
    edgew_kernel<<<ngrid4, 256, 0, stream>>>(el, er, rowptr, srcs, wbuf, N);
    agg_kernel<<<ngrid4, 256, 0, stream>>>(featb, wbuf, rowptr, srcs,
                                           Afh, Afl, out, nullptr, nullptr, N);
}

// Round 6
// 332.874 us; speedup vs baseline: 1.1828x; 1.1828x over previous
//
#include <hip/hip_runtime.h>
#include <hip/hip_bf16.h>

#define N_NODES 50000
#define N_EDGES 800000
#define NHEAD 4
#define DHEAD 64
#define FDIM 256   // NHEAD*DHEAD == in_feats == out_feats
#define SCANB 1024
#define NSCAN ((N_NODES + SCANB - 1) / SCANB)   // 49

typedef __attribute__((ext_vector_type(8))) short bfrag8;   // 8 bf16 (4 VGPRs)
typedef __attribute__((ext_vector_type(4))) float f32x4;    // 4 fp32 acc

// ---------------- bf16 helpers ----------------
__device__ __forceinline__ unsigned f2bf_rne(float x) {
    unsigned u = __float_as_uint(x);
    return (u + 0x7fffu + ((u >> 16) & 1u)) >> 16;
}
__device__ __forceinline__ float bf2f(unsigned u) {
    return __uint_as_float(u << 16);
}

// ---------------- CSR build ----------------
__global__ void degree_kernel(const int* __restrict__ dst, int* __restrict__ cnt, int E) {
    int e = blockIdx.x * 256 + threadIdx.x;
    if (e < E) atomicAdd(&cnt[dst[e]], 1);
}

__global__ __launch_bounds__(1024) void scan1_kernel(const int* __restrict__ cnt,
                                                     int* __restrict__ partial,
                                                     int* __restrict__ bsum, int N) {
    __shared__ int sdata[SCANB];
    int i = blockIdx.x * SCANB + (int)threadIdx.x;
    int v = (i < N) ? cnt[i] : 0;
    sdata[threadIdx.x] = v;
    __syncthreads();
    for (int off = 1; off < SCANB; off <<= 1) {
        int t = (threadIdx.x >= (unsigned)off) ? sdata[threadIdx.x - off] : 0;
        __syncthreads();
        sdata[threadIdx.x] += t;
        __syncthreads();
    }
    if (i < N) partial[i] = sdata[threadIdx.x];
    if (threadIdx.x == SCANB - 1) bsum[blockIdx.x] = sdata[SCANB - 1];
}

__global__ void scan2_kernel(const int* __restrict__ bsum, int* __restrict__ boff, int nb) {
    int lane = threadIdx.x;   // 64 threads
    int v = (lane < nb) ? bsum[lane] : 0;
#pragma unroll
    for (int off = 1; off < 64; off <<= 1) {
        int o = __shfl_up(v, off, 64);
        if (lane >= off) v += o;
    }
    int excl = __shfl_up(v, 1, 64);
    if (lane == 0) excl = 0;
    if (lane < nb) boff[lane] = excl;
}

__global__ __launch_bounds__(1024) void scan3_kernel(const int* __restrict__ partial,
                                                     const int* __restrict__ boff,
                                                     int* __restrict__ rowptr,
                                                     int* __restrict__ cursor, int N) {
    int i = blockIdx.x * SCANB + (int)threadIdx.x;
    if (i < N) {
        int inc = partial[i] + boff[blockIdx.x];
        rowptr[i + 1] = inc;
        if (i + 1 < N) cursor[i + 1] = inc;
    }
    if (i == 0) { rowptr[0] = 0; cursor[0] = 0; }
}

__global__ void scatter_kernel(const int* __restrict__ src, const int* __restrict__ dst,
                               int* __restrict__ cursor, int* __restrict__ srcs, int E) {
    int e = blockIdx.x * 256 + threadIdx.x;
    if (e < E) {
        int pos = atomicAdd(&cursor[dst[e]], 1);
        srcs[pos] = src[e];
    }
}

// ---------------- W split+transpose: B[256][256] fp32 -> Bth/Btl[n][k] bf16 ----------------
__global__ __launch_bounds__(256) void bconv_kernel(const float* __restrict__ B,
                                                    ushort* __restrict__ Bth,
                                                    ushort* __restrict__ Btl) {
    __shared__ ushort th[16][264], tl[16][264];
    int k0 = blockIdx.x * 16;
    int n = threadIdx.x;
#pragma unroll
    for (int k = 0; k < 16; ++k) {
        float v = B[(size_t)(k0 + k) * 256 + n];
        unsigned hb = f2bf_rne(v);
        th[k][n] = (ushort)hb;
        tl[k][n] = (ushort)(__float_as_uint(v - bf2f(hb)) >> 16);
    }
    __syncthreads();
    ushort oh[16], ol[16];
#pragma unroll
    for (int k = 0; k < 16; ++k) { oh[k] = th[k][n]; ol[k] = tl[k][n]; }
#pragma unroll
    for (int q = 0; q < 4; ++q) {
        *reinterpret_cast<ushort4*>(Bth + (size_t)n * 256 + k0 + q * 4) =
            make_ushort4(oh[q*4+0], oh[q*4+1], oh[q*4+2], oh[q*4+3]);
        *reinterpret_cast<ushort4*>(Btl + (size_t)n * 256 + k0 + q * 4) =
            make_ushort4(ol[q*4+0], ol[q*4+1], ol[q*4+2], ol[q*4+3]);
    }
}

// ---------------- GEMM: Cb[M,256](bf16) = A @ (Bh+Bl), split-bf16 MFMA ----------------
// SPLITA=1: A is fp32, split inline during staging (layer 1).
// SPLITA=0: A pre-split hi/lo bf16 (layer 2, produced by agg1).
template <int SPLITA>
__global__ __launch_bounds__(256) void gemm_mfma_kernel(const float* __restrict__ Af,
                                                        const ushort* __restrict__ Ahg,
                                                        const ushort* __restrict__ Alg,
                                                        const ushort* __restrict__ Bth,
                                                        const ushort* __restrict__ Btl,
                                                        ushort* __restrict__ Cb, int M) {
    __shared__ ushort Ah[128][40], Al[128][40];   // [m][k], 80B row stride (bank-spread)
    __shared__ ushort Bh[128][40], Bl[128][40];   // [n][k]
    const int t = threadIdx.x;
    const int lane = t & 63, wave = t >> 6;
    const int wr = wave >> 1, wc = wave & 1;
    const int row0 = blockIdx.x * 128;
    const int col0 = blockIdx.y * 128;

    f32x4 acc[4][4];
#pragma unroll
    for (int i = 0; i < 4; ++i)
#pragma unroll
        for (int j = 0; j < 4; ++j) { acc[i][j].x = 0.f; acc[i][j].y = 0.f; acc[i][j].z = 0.f; acc[i][j].w = 0.f; }

    const int srow = t >> 1;            // 0..127
    const int skoff = (t & 1) * 16;     // 0 or 16
    int arow = row0 + srow; if (arow >= M) arow = M - 1;   // clamp; stores guarded
    const size_t abase = (size_t)arow * 256 + skoff;
    const size_t bbase = (size_t)(col0 + srow) * 256 + skoff;

    float4 af0, af1, af2, af3;          // SPLITA: 16 fp32 of A
    uint4 r0, r1, r2, r3;               // !SPLITA: Ah/Al 16B each
    uint4 r4, r5, r6, r7;               // B hi/lo

#define LOADK(kk)                                                              \
    do {                                                                       \
        if constexpr (SPLITA) {                                                \
            const float4* pa = reinterpret_cast<const float4*>(Af + abase + (kk)); \
            af0 = pa[0]; af1 = pa[1]; af2 = pa[2]; af3 = pa[3];                \
        } else {                                                               \
            r0 = *reinterpret_cast<const uint4*>(Ahg + abase + (kk));          \
            r1 = *reinterpret_cast<const uint4*>(Ahg + abase + (kk) + 8);      \
            r2 = *reinterpret_cast<const uint4*>(Alg + abase + (kk));          \
            r3 = *reinterpret_cast<const uint4*>(Alg + abase + (kk) + 8);      \
        }                                                                      \
        r4 = *reinterpret_cast<const uint4*>(Bth + bbase + (kk));              \
        r5 = *reinterpret_cast<const uint4*>(Bth + bbase + (kk) + 8);          \
        r6 = *reinterpret_cast<const uint4*>(Btl + bbase + (kk));              \
        r7 = *reinterpret_cast<const uint4*>(Btl + bbase + (kk) + 8);          \
    } while (0)

    LOADK(0);
#pragma unroll
    for (int kk = 0; kk < 256; kk += 32) {
        if (kk) __syncthreads();
        if constexpr (SPLITA) {
            float v[16];
            v[0]=af0.x; v[1]=af0.y; v[2]=af0.z; v[3]=af0.w;
            v[4]=af1.x; v[5]=af1.y; v[6]=af1.z; v[7]=af1.w;
            v[8]=af2.x; v[9]=af2.y; v[10]=af2.z; v[11]=af2.w;
            v[12]=af3.x; v[13]=af3.y; v[14]=af3.z; v[15]=af3.w;
            ushort hh[16], ll[16];
#pragma unroll
            for (int q = 0; q < 16; ++q) {
                unsigned hb = f2bf_rne(v[q]);
                hh[q] = (ushort)hb;
                ll[q] = (ushort)(__float_as_uint(v[q] - bf2f(hb)) >> 16);
            }
#pragma unroll
            for (int q = 0; q < 4; ++q) {
                *reinterpret_cast<ushort4*>(&Ah[srow][skoff + q * 4]) =
                    make_ushort4(hh[q*4+0], hh[q*4+1], hh[q*4+2], hh[q*4+3]);
                *reinterpret_cast<ushort4*>(&Al[srow][skoff + q * 4]) =
                    make_ushort4(ll[q*4+0], ll[q*4+1], ll[q*4+2], ll[q*4+3]);
            }
        } else {
            *reinterpret_cast<uint4*>(&Ah[srow][skoff])     = r0;
            *reinterpret_cast<uint4*>(&Ah[srow][skoff + 8]) = r1;
            *reinterpret_cast<uint4*>(&Al[srow][skoff])     = r2;
            *reinterpret_cast<uint4*>(&Al[srow][skoff + 8]) = r3;
        }
        *reinterpret_cast<uint4*>(&Bh[srow][skoff])     = r4;
        *reinterpret_cast<uint4*>(&Bh[srow][skoff + 8]) = r5;
        *reinterpret_cast<uint4*>(&Bl[srow][skoff])     = r6;
        *reinterpret_cast<uint4*>(&Bl[srow][skoff + 8]) = r7;
        __syncthreads();
        if (kk + 32 < 256) LOADK(kk + 32);   // latency hides under MFMA below

        const int kg = (lane >> 4) * 8;
        const int rsel = lane & 15;
        bfrag8 afh[4], afl[4], bfh[4], bfl[4];
#pragma unroll
        for (int i = 0; i < 4; ++i) {
            afh[i] = *reinterpret_cast<const bfrag8*>(&Ah[wr * 64 + i * 16 + rsel][kg]);
            afl[i] = *reinterpret_cast<const bfrag8*>(&Al[wr * 64 + i * 16 + rsel][kg]);
        }
#pragma unroll
        for (int j = 0; j < 4; ++j) {
            bfh[j] = *reinterpret_cast<const bfrag8*>(&Bh[wc * 64 + j * 16 + rsel][kg]);
            bfl[j] = *reinterpret_cast<const bfrag8*>(&Bl[wc * 64 + j * 16 + rsel][kg]);
        }
#pragma unroll
        for (int i = 0; i < 4; ++i)
#pragma unroll
            for (int j = 0; j < 4; ++j) {
                acc[i][j] = __builtin_amdgcn_mfma_f32_16x16x32_bf16(afh[i], bfh[j], acc[i][j], 0, 0, 0);
                acc[i][j] = __builtin_amdgcn_mfma_f32_16x16x32_bf16(afh[i], bfl[j], acc[i][j], 0, 0, 0);
                acc[i][j] = __builtin_amdgcn_mfma_f32_16x16x32_bf16(afl[i], bfh[j], acc[i][j], 0, 0, 0);
            }
    }
#undef LOADK
    const int ccol = lane & 15;
    const int crow = (lane >> 4) * 4;
#pragma unroll
    for (int i = 0; i < 4; ++i) {
#pragma unroll
        for (int r = 0; r < 4; ++r) {
            int row = row0 + wr * 64 + i * 16 + crow + r;
            if (row >= M) continue;
#pragma unroll
            for (int j = 0; j < 4; ++j) {
                int col = col0 + wc * 64 + j * 16 + ccol;
                float val = (r == 0) ? acc[i][j].x : (r == 1) ? acc[i][j].y : (r == 2) ? acc[i][j].z : acc[i][j].w;
                Cb[(size_t)row * 256 + col] = (ushort)f2bf_rne(val);
            }
        }
    }
}

// ---------------- el/er: per-node head dots (bf16 feat) ----------------
__global__ void eler_kernel(const ushort* __restrict__ featb, const float* __restrict__ al,
                            const float* __restrict__ ar, float* __restrict__ el,
                            float* __restrict__ er, int N) {
    int node = blockIdx.x * 4 + (threadIdx.x >> 6);
    if (node >= N) return;
    int lane = threadIdx.x & 63;
    ushort4 fu = *reinterpret_cast<const ushort4*>(featb + (size_t)node * FDIM + lane * 4);
    float f0 = bf2f(fu.x), f1 = bf2f(fu.y), f2 = bf2f(fu.z), f3 = bf2f(fu.w);
    float4 a = *reinterpret_cast<const float4*>(al + lane * 4);
    float4 b = *reinterpret_cast<const float4*>(ar + lane * 4);
    float pl = f0 * a.x + f1 * a.y + f2 * a.z + f3 * a.w;
    float pr = f0 * b.x + f1 * b.y + f2 * b.z + f3 * b.w;
#pragma unroll
    for (int m = 1; m < 16; m <<= 1) {
        pl += __shfl_xor(pl, m, 64);
        pr += __shfl_xor(pr, m, 64);
    }
    if ((lane & 15) == 0) {
        int h = lane >> 4;
        el[node * NHEAD + h] = pl;
        er[node * NHEAD + h] = pr;
    }
}

// ---------------- fused softmax + aggregation, one wave per node ----------------
// Phase A: stats with (16 edges x 4 heads) on 64 lanes — each exp computed once.
// Phase B: per chunk, each lane computes ONE weight; shuffle-broadcast into the
//          gather loop (no w materialization, no redundant exp), 4 accumulators.
__global__ __launch_bounds__(256) void agg_kernel(
        const ushort* __restrict__ featb, const float* __restrict__ el,
        const float* __restrict__ er, const int* __restrict__ rowptr,
        const int* __restrict__ srcs,
        const ushort* __restrict__ resid_h, const ushort* __restrict__ resid_l,
        float* __restrict__ outf, ushort* __restrict__ outh, ushort* __restrict__ outl,
        int N) {
    int node = blockIdx.x * 4 + (threadIdx.x >> 6);
    if (node >= N) return;
    int lane = threadIdx.x & 63;
    int h4 = lane & 3;        // head for stats/weights
    int eo = lane >> 2;       // edge slot within 16-chunk
    int head = lane >> 4;     // head for gather (feature layout)
    float erh = er[(size_t)node * NHEAD + h4];
    int beg = rowptr[node], end = rowptr[node + 1];

    // ---- phase A: max & denom per head ----
    float m = -1e30f, ls = 0.f;
    for (int base = beg; base < end; base += 16) {
        int p = base + eo;
        float x = -1e30f;
        if (p < end) {
            int s = srcs[p];
            float t = el[(size_t)s * NHEAD + h4] + erh;
            x = t > 0.f ? t : 0.2f * t;
        }
        float cm = x;   // reduce over the 16 lanes sharing head h4
        cm = fmaxf(cm, __shfl_xor(cm, 4, 64));
        cm = fmaxf(cm, __shfl_xor(cm, 8, 64));
        cm = fmaxf(cm, __shfl_xor(cm, 16, 64));
        cm = fmaxf(cm, __shfl_xor(cm, 32, 64));
        float mn = fmaxf(m, cm);
        ls = ls * __expf(m - mn) + ((p < end) ? __expf(x - mn) : 0.f);
        m = mn;
    }
    ls += __shfl_xor(ls, 4, 64);
    ls += __shfl_xor(ls, 8, 64);
    ls += __shfl_xor(ls, 16, 64);
    ls += __shfl_xor(ls, 32, 64);
    float dinv = ls > 0.f ? 1.0f / ls : 0.f;

    // ---- phase B: weighted gather with shuffle-broadcast weights ----
    f32x4 a0 = {0.f, 0.f, 0.f, 0.f}, a1 = a0, a2 = a0, a3 = a0;
    for (int base = beg; base < end; base += 16) {
        int p = base + eo;
        int smine = 0;
        float wmine = 0.f;
        if (p < end) {
            smine = srcs[p];
            float t = el[(size_t)smine * NHEAD + h4] + erh;
            t = t > 0.f ? t : 0.2f * t;
            wmine = __expf(t - m) * dinv;
        }
        int jmax = end - base; if (jmax > 16) jmax = 16;   // wave-uniform bound
        int j = 0;
        for (; j + 3 < jmax; j += 4) {
            int sl0 = 4 * j + head;
            int s0 = __shfl(smine, sl0, 64);
            int s1 = __shfl(smine, sl0 + 4, 64);
            int s2 = __shfl(smine, sl0 + 8, 64);
            int s3 = __shfl(smine, sl0 + 12, 64);
            float w0 = __shfl(wmine, sl0, 64);
            float w1 = __shfl(wmine, sl0 + 4, 64);
            float w2 = __shfl(wmine, sl0 + 8, 64);
            float w3 = __shfl(wmine, sl0 + 12, 64);
            ushort4 f0 = *reinterpret_cast<const ushort4*>(featb + (size_t)s0 * FDIM + lane * 4);
            ushort4 f1 = *reinterpret_cast<const ushort4*>(featb + (size_t)s1 * FDIM + lane * 4);
            ushort4 f2 = *reinterpret_cast<const ushort4*>(featb + (size_t)s2 * FDIM + lane * 4);
            ushort4 f3 = *reinterpret_cast<const ushort4*>(featb + (size_t)s3 * FDIM + lane * 4);
            a0.x = fmaf(w0, bf2f(f0.x), a0.x); a0.y = fmaf(w0, bf2f(f0.y), a0.y);
            a0.z = fmaf(w0, bf2f(f0.z), a0.z); a0.w = fmaf(w0, bf2f(f0.w), a0.w);
            a1.x = fmaf(w1, bf2f(f1.x), a1.x); a1.y = fmaf(w1, bf2f(f1.y), a1.y);
            a1.z = fmaf(w1, bf2f(f1.z), a1.z); a1.w = fmaf(w1, bf2f(f1.w), a1.w);
            a2.x = fmaf(w2, bf2f(f2.x), a2.x); a2.y = fmaf(w2, bf2f(f2.y), a2.y);
            a2.z = fmaf(w2, bf2f(f2.z), a2.z); a2.w = fmaf(w2, bf2f(f2.w), a2.w);
            a3.x = fmaf(w3, bf2f(f3.x), a3.x); a3.y = fmaf(w3, bf2f(f3.y), a3.y);
            a3.z = fmaf(w3, bf2f(f3.z), a3.z); a3.w = fmaf(w3, bf2f(f3.w), a3.w);
        }
        for (; j < jmax; ++j) {
            int sl = 4 * j + head;
            int s0 = __shfl(smine, sl, 64);
            float w0 = __shfl(wmine, sl, 64);
            ushort4 f0 = *reinterpret_cast<const ushort4*>(featb + (size_t)s0 * FDIM + lane * 4);
            a0.x = fmaf(w0, bf2f(f0.x), a0.x); a0.y = fmaf(w0, bf2f(f0.y), a0.y);
            a0.z = fmaf(w0, bf2f(f0.z), a0.z); a0.w = fmaf(w0, bf2f(f0.w), a0.w);
        }
    }
    float4 acc = make_float4(a0.x + a1.x + a2.x + a3.x, a0.y + a1.y + a2.y + a3.y,
                             a0.z + a1.z + a2.z + a3.z, a0.w + a1.w + a2.w + a3.w);

    if (resid_h) {
        ushort4 rh = *reinterpret_cast<const ushort4*>(resid_h + (size_t)node * FDIM + lane * 4);
        ushort4 rl = *reinterpret_cast<const ushort4*>(resid_l + (size_t)node * FDIM + lane * 4);
        acc.x += bf2f(rh.x) + bf2f(rl.x);
        acc.y += bf2f(rh.y) + bf2f(rl.y);
        acc.z += bf2f(rh.z) + bf2f(rl.z);
        acc.w += bf2f(rh.w) + bf2f(rl.w);
    }
    acc.x = acc.x > 0.f ? acc.x : expm1f(acc.x);
    acc.y = acc.y > 0.f ? acc.y : expm1f(acc.y);
    acc.z = acc.z > 0.f ? acc.z : expm1f(acc.z);
    acc.w = acc.w > 0.f ? acc.w : expm1f(acc.w);

    if (outf) {
        *reinterpret_cast<float4*>(outf + (size_t)node * FDIM + lane * 4) = acc;
    } else {
        unsigned h0 = f2bf_rne(acc.x), h1 = f2bf_rne(acc.y), h2 = f2bf_rne(acc.z), h3 = f2bf_rne(acc.w);
        *reinterpret_cast<ushort4*>(outh + (size_t)node * FDIM + lane * 4) =
            make_ushort4((ushort)h0, (ushort)h1, (ushort)h2, (ushort)h3);
        *reinterpret_cast<ushort4*>(outl + (size_t)node * FDIM + lane * 4) = make_ushort4(
            (ushort)(__float_as_uint(acc.x - bf2f(h0)) >> 16),
            (ushort)(__float_as_uint(acc.y - bf2f(h1)) >> 16),
            (ushort)(__float_as_uint(acc.z - bf2f(h2)) >> 16),
            (ushort)(__float_as_uint(acc.w - bf2f(h3)) >> 16));
    }
}

// ---------------- launch ----------------
extern "C" void kernel_launch(void* const* d_in, const int* in_sizes, int n_in,
                              void* d_out, int out_size, void* d_ws, size_t ws_size,
                              hipStream_t stream) {
    const float* features = (const float*)d_in[0];
    const int*   src      = (const int*)d_in[1];
    const int*   dst      = (const int*)d_in[2];
    const float* W1       = (const float*)d_in[3];
    const float* al1      = (const float*)d_in[4];
    const float* ar1      = (const float*)d_in[5];
    const float* W2       = (const float*)d_in[6];
    const float* al2      = (const float*)d_in[7];
    const float* ar2      = (const float*)d_in[8];
    float* out = (float*)d_out;

    const int N = N_NODES, E = N_EDGES;

    char* ws = (char*)d_ws;
    size_t off = 0;
    auto alloc = [&](size_t bytes) -> void* {
        void* p = ws + off;
        off = (off + bytes + 255) & ~(size_t)255;
        return p;
    };
    ushort* featb  = (ushort*)alloc((size_t)N * FDIM * 2);
    ushort* Afh    = (ushort*)alloc((size_t)N * FDIM * 2);   // layer-1 output hi (agg1 out)
    ushort* Afl    = (ushort*)alloc((size_t)N * FDIM * 2);   // layer-1 output lo
    float*  el     = (float*)alloc((size_t)N * NHEAD * 4);
    float*  er     = (float*)alloc((size_t)N * NHEAD * 4);
    int*    rowptr = (int*)alloc((size_t)(N + 1) * 4);
    int*    cnt    = (int*)alloc((size_t)N * 4);
    int*    cursor = (int*)alloc((size_t)N * 4);
    int*    partial= (int*)alloc((size_t)N * 4);
    int*    bsum   = (int*)alloc((size_t)NSCAN * 4);
    int*    boff   = (int*)alloc((size_t)NSCAN * 4);
    int*    srcs   = (int*)alloc((size_t)E * 4);
    ushort* Bth    = (ushort*)alloc((size_t)256 * 256 * 2);
    ushort* Btl    = (ushort*)alloc((size_t)256 * 256 * 2);

    const int egrid = (E + 255) / 256;
    const int ngrid4 = (N + 3) / 4;

    // ---- CSR build (by dst) ----
    hipMemsetAsync(cnt, 0, (size_t)N * 4, stream);
    degree_kernel<<<egrid, 256, 0, stream>>>(dst, cnt, E);
    scan1_kernel<<<NSCAN, SCANB, 0, stream>>>(cnt, partial, bsum, N);
    scan2_kernel<<<1, 64, 0, stream>>>(bsum, boff, NSCAN);
    scan3_kernel<<<NSCAN, SCANB, 0, stream>>>(partial, boff, rowptr, cursor, N);
    scatter_kernel<<<egrid, 256, 0, stream>>>(src, dst, cursor, srcs, E);

    dim3 ggrid((N + 127) / 128, 2);

    // ---- layer 1 (A = fp32 features, split inline in GEMM) ----
    bconv_kernel<<<16, 256, 0, stream>>>(W1, Bth, Btl);
    gemm_mfma_kernel<1><<<ggrid, 256, 0, stream>>>(features, nullptr, nullptr, Bth, Btl, featb, N);
    eler_kernel<<<ngrid4, 256, 0, stream>>>(featb, al1, ar1, el, er, N);
    agg_kernel<<<ngrid4, 256, 0, stream>>>(featb, el, er, rowptr, srcs,
                                           nullptr, nullptr, nullptr, Afh, Afl, N);

    // ---- layer 2 (A = layer-1 output pre-split; residual = hi+lo) ----
    bconv_kernel<<<16, 256, 0, stream>>>(W2, Bth, Btl);
    gemm_mfma_kernel<0><<<ggrid, 256, 0, stream>>>(nullptr, Afh, Afl, Bth, Btl, featb, N);
    eler_kernel<<<ngrid4, 256, 0, stream>>>(featb, al2, ar2, el, er, N);
    agg_kernel<<<ngrid4, 256, 0, stream>>>(featb, el, er, rowptr, srcs,
                                           Afh, Afl, out, nullptr, nullptr, N);
}